// Round 18
// baseline (223.130 us; speedup 1.0000x reference)
//
#include <hip/hip_runtime.h>

// Forbid FMA contraction EVERYWHERE: distances must be bit-identical to
// numpy's unfused ((dx*dx + dy*dy) + dz*dz) in main loop AND fallback.
#pragma clang fp contract(off)

typedef unsigned long long u64;
typedef unsigned int u32;
typedef unsigned short u16;
typedef float f32x2 __attribute__((ext_vector_type(2)));

#define BB 8
#define LL 2048
#define MM 4096
#define KK 25
#define WPB 16           // waves (queries) per block
#define TPB 1024
#define CAP 3072         // compacted-valid capacity (V ~ 2048 +- 32; P(V>CAP)~0)
#define SENT  0xFFFFFFFFFFFFFFFFull
#define SENTH 0xFFFFFFFFu   // exhausted marker for value words (> inf-bits+1)

// Wave64 min-reduce -> wave-uniform scalar (proven round-9 DPP ladder).
static __device__ __forceinline__ u32 wave_min_u32(u32 x) {
    u32 t;
    t = (u32)__builtin_amdgcn_update_dpp(0, (int)x, 0xB1, 0xF, 0xF, true);   // xor1
    x = t < x ? t : x;
    t = (u32)__builtin_amdgcn_update_dpp(0, (int)x, 0x4E, 0xF, 0xF, true);   // xor2
    x = t < x ? t : x;
    t = (u32)__builtin_amdgcn_update_dpp(0, (int)x, 0x141, 0xF, 0xF, true);  // half-row mirror
    x = t < x ? t : x;
    t = (u32)__builtin_amdgcn_update_dpp(0, (int)x, 0x140, 0xF, 0xF, true);  // row mirror
    x = t < x ? t : x;
    t = (u32)__builtin_amdgcn_update_dpp((int)x, (int)x, 0x142, 0xF, 0xF, false); // row_bcast15
    x = t < x ? t : x;
    t = (u32)__builtin_amdgcn_update_dpp((int)x, (int)x, 0x143, 0xF, 0xF, false); // row_bcast31
    x = t < x ? t : x;
    return (u32)__builtin_amdgcn_readlane((int)x, 63);
}

// ===========================================================================
// ROUND 29: MEASUREMENT ROUND #2 (pre-committed in r28's falsifier).
// Ledger: staging+main = 24.6us (r20 stub, structure identical to r28's
// main), full r28 = 42.2 => selection+fire+merge = 17.6us by subtraction,
// vs ~4us static estimate. Two attribution failures in a row on this
// boundary -> measure, don't theorize.
//  * knn_selstub (grid 4096 = 4x): r28 staging + main + selection +
//    fire-ladder, keep-alive on myk (transitively keeps sExt scatter, rank
//    loop, sR writes, ladder), NO global writes. selection+fire =
//    stub/4 - 24.6.
//  * knn_kernel (grid 1024): r28 VERBATIM (42.2us, absmax 0).
// Decision rule: stub/4 ~ 37-41 => selection is the sink -> restructure it
// (rank via in-register ballot counting, kill the sExt round-trip).
// stub/4 ~ 28-30 => phases non-additive (co-scheduling interference) ->
// one structural occupancy attempt, then evaluate roofline.
// ===========================================================================

__global__ void __launch_bounds__(TPB, 8) knn_selstub(
    const float* __restrict__ CB, const float* __restrict__ maskA,
    const float* __restrict__ Y, const int* __restrict__ Yt,
    const int* __restrict__ Ym)
{
    __shared__ __align__(16) float sX[CAP];
    __shared__ __align__(16) float sY[CAP];
    __shared__ __align__(16) float sZ[CAP];
    __shared__ u16 sP16[CAP];
    __shared__ u16 sMidx[64];
    __shared__ int sWinc[16];
    __shared__ int sWbase[16];
    __shared__ int sVtot;
    __shared__ u64 sExt[WPB][64];
    __shared__ u64 sR[WPB][KK];

    const int tid  = threadIdx.x;
    const int lane = tid & 63;
    const int wv   = tid >> 6;
    const int blk  = blockIdx.x;
    const int b    = (blk >> 7) & 7;  // wraps 4x over the 8 batches
    const int qg   = blk & 127;

    const float* Yb  = Y  + (size_t)b * MM * 3;
    const int*   Ymb = Ym + (size_t)b * MM;

    const int p0 = tid << 2;
    const float4 f0 = *(const float4*)(Yb + 3 * p0);
    const float4 f1 = *(const float4*)(Yb + 3 * p0 + 4);
    const float4 f2 = *(const float4*)(Yb + 3 * p0 + 8);
    const int4   m4 = *(const int4*)(Ymb + p0);
    const int v0 = (m4.x != 0), v1 = (m4.y != 0), v2 = (m4.z != 0), v3 = (m4.w != 0);
    const int cnt0 = v0 + v1 + v2 + v3;

    int inc = cnt0;
#pragma unroll
    for (int off = 1; off < 64; off <<= 1) {
        const int t = __shfl_up(inc, off, 64);
        if (lane >= off) inc += t;
    }
    if (lane == 63) sWinc[wv] = inc;
    __syncthreads();
    if (tid < 16) {
        const int x = sWinc[tid];
        int ix = x;
#pragma unroll
        for (int off = 1; off < 16; off <<= 1) {
            const int t = __shfl_up(ix, off, 16);
            if (tid >= off) ix += t;
        }
        sWbase[tid] = ix - x;
        if (tid == 15) sVtot = ix;
    }
    __syncthreads();

    {
        int bs = sWbase[wv] + inc - cnt0;
        int mb = p0 - bs;
        if (v0) { sX[bs]=f0.x; sY[bs]=f0.y; sZ[bs]=f0.z; sP16[bs]=(u16)(p0+0); bs++; }
        else    { if (mb < 64) sMidx[mb] = (u16)(p0 + 0); mb++; }
        if (v1) { sX[bs]=f0.w; sY[bs]=f1.x; sZ[bs]=f1.y; sP16[bs]=(u16)(p0+1); bs++; }
        else    { if (mb < 64) sMidx[mb] = (u16)(p0 + 1); mb++; }
        if (v2) { sX[bs]=f1.z; sY[bs]=f1.w; sZ[bs]=f2.x; sP16[bs]=(u16)(p0+2); bs++; }
        else    { if (mb < 64) sMidx[mb] = (u16)(p0 + 2); mb++; }
        if (v3) { sX[bs]=f2.y; sY[bs]=f2.z; sZ[bs]=f2.w; sP16[bs]=(u16)(p0+3); bs++; }
        else    { if (mb < 64) sMidx[mb] = (u16)(p0 + 3); mb++; }
    }
    const int V  = sVtot;
    const int NJ = (V + 127) >> 7;
    for (int c = V + tid; c < (NJ << 7); c += TPB) {
        sX[c] = __builtin_inff(); sY[c] = 0.0f; sZ[c] = 0.0f; sP16[c] = 4095;
    }
    __syncthreads();

    const int l = qg * WPB + wv;
    const int q = b * LL + l;

    if (maskA[q] == 0.0f) return;      // stub: no writes anywhere

    const float cx = CB[3 * q + 0];
    const float cy = CB[3 * q + 1];
    const float cz = CB[3 * q + 2];

    float v1f = 3.0e38f, v2f = 3.0e38f, v3f = 3.0e38f, v4f = 3.0e38f;
    u32 J = 0u;
    const u32 SEL1 = 0x06050400u;
    const u32 SEL2 = 0x06050004u;
    const u32 SEL3 = 0x06000504u;
    const u32 SEL4 = 0x00060504u;
    auto ins = [&](float v, u32 id) {
        const bool c1 = v < v1f, c2 = v < v2f, c3 = v < v3f, c4 = v < v4f;
        const u32 sel = c1 ? SEL1 : (c2 ? SEL2 : (c3 ? SEL3 : SEL4));
        const u32 Jp  = __builtin_amdgcn_perm(J, id, sel);
        const float n2 = __builtin_amdgcn_fmed3f(v, v1f, v2f);
        const float n3 = __builtin_amdgcn_fmed3f(v, v2f, v3f);
        const float n4 = __builtin_amdgcn_fmed3f(v, v3f, v4f);
        v1f = fminf(v, v1f);
        v2f = n2; v3f = n3; v4f = n4;
        J = c4 ? Jp : J;
    };

    const f32x2 cxx = {cx, cx}, cyy = {cy, cy}, czz = {cz, cz};
#pragma unroll 4
    for (int j = 0; j < NJ; ++j) {
        const int base = (j << 7) + (lane << 1);
        const f32x2 xp = *(const f32x2*)&sX[base];
        const f32x2 yp = *(const f32x2*)&sY[base];
        const f32x2 zp = *(const f32x2*)&sZ[base];
        const f32x2 dx = cxx - xp;
        const f32x2 dy = cyy - yp;
        const f32x2 dz = czz - zp;
        const f32x2 dsq = (dx * dx + dy * dy) + dz * dz;
        ins(dsq.x, (u32)(j << 1));
        ins(dsq.y, (u32)((j << 1) | 1));
    }

    auto slotof = [&](u32 id) -> u32 {
        return ((id >> 1) << 7) | (u32)(lane << 1) | (id & 1u);
    };

    const u32 s1 = slotof( J        & 0xFFu);
    const u32 s2 = slotof((J >>  8) & 0xFFu);
    const u32 s3 = slotof((J >> 16) & 0xFFu);
    const u32 s4 = slotof((J >> 24) & 0xFFu);
    u32 h1 = __float_as_uint(v1f) + 1u;
    u32 h2 = __float_as_uint(v2f) + 1u;
    u32 h3 = __float_as_uint(v3f) + 1u;
    u32 h4 = __float_as_uint(v4f) + 1u;
    u64 lref = ((u64)h4 << 32) | s4;

    bool ladder = false;
    int  rstart = 0;
    {
        const u32 T = wave_min_u32(h4);
        const bool c1 = (h1 <= T), c2 = (h2 <= T), c3 = (h3 <= T), c4 = (h4 <= T);
        const u64 b1 = __ballot(c1), b2 = __ballot(c2);
        const u64 b3 = __ballot(c3), b4 = __ballot(c4);
        const int n1 = __popcll(b1), n2 = __popcll(b2), n3 = __popcll(b3);
        const int total = n1 + n2 + n3 + __popcll(b4);
        if (total > 64) {
            ladder = true;
        } else {
            const u64 below = (1ull << lane) - 1ull;
            u64* sE = sExt[wv];
            sE[lane] = SENT;
            if (lane == 24) sR[wv][24] = SENT;
            int pos = __popcll(b1 & below);
            if (c1) sE[pos] = ((u64)h1 << 32) | s1;
            pos = n1 + __popcll(b2 & below);
            if (c2) sE[pos] = ((u64)h2 << 32) | s2;
            pos = n1 + n2 + __popcll(b3 & below);
            if (c3) sE[pos] = ((u64)h3 << 32) | s3;
            pos = n1 + n2 + n3 + __popcll(b4 & below);
            if (c4) sE[pos] = ((u64)h4 << 32) | s4;
            const u64 mk = sE[lane];
            int rank = 0;
            const int tot = (total + 7) & ~7;
#pragma unroll 8
            for (int i = 0; i < tot; ++i)
                rank += (sE[i] < mk) ? 1 : 0;
            if (rank < KK && mk != SENT) sR[wv][rank] = mk;
            const u64 K25 = sR[wv][24];
            if (__any(lref < K25)) {
                const int scnt = (h1 < T) + (h2 < T) + (h3 < T) + (h4 < T);
                rstart = __popcll(__ballot(h1 < T)) + __popcll(__ballot(h2 < T))
                       + __popcll(__ballot(h3 < T)) + __popcll(__ballot(h4 < T));
#pragma unroll
                for (int k = 0; k < 4; ++k)
                    if (k < scnt) { h1 = h2; h2 = h3; h3 = h4; h4 = SENTH; J >>= 8; }
                ladder = true;
            }
        }
    }

    if (ladder) {
#pragma unroll 1
        for (int it = rstart; it < KK; ++it) {
            if (__any(h1 == SENTH)) {
                const bool need = (h1 == SENTH);
                u64 found = SENT;
                const int NI = NJ << 1;
#pragma unroll 4
                for (int id = 0; id < NI; ++id) {
                    const u32 s = slotof((u32)id);
                    const float dx = cx - sX[s];
                    const float dy = cy - sY[s];
                    const float dz = cz - sZ[s];
                    const float v = (dx * dx + dy * dy) + dz * dz;
                    const u64 key = ((u64)(__float_as_uint(v) + 1u) << 32) | s;
                    if (key > lref && key < found) found = key;
                }
                if (need) {
                    const u32 s = (u32)found & 0xFFFFu;
                    h1 = (u32)(found >> 32);
                    J = (J & ~0xFFu) | (((s >> 7) << 1) | (s & 1u));
                    lref = found;
                }
            }
            const u32 bv = wave_min_u32(h1);
            const u64 ball = __ballot(h1 == bv);
            bool win = (h1 == bv);
            if (__popcll(ball) != 1) {
                const u32 vl = slotof(J & 0xFFu);
                u32 cp = win ? vl : 0xFFFFFFFFu;
#pragma unroll
                for (int off = 32; off; off >>= 1) {
                    const u32 o = __shfl_xor(cp, off, 64);
                    cp = (o < cp) ? o : cp;
                }
                win = win && (vl == cp);
            }
            if (win) {
                sR[wv][it] = ((u64)h1 << 32) | slotof(J & 0xFFu);
                h1 = h2; h2 = h3; h3 = h4; h4 = SENTH;
                J >>= 8;
            }
        }
    }

    u64 myk = 0;
    if (lane < KK) myk = sR[wv][lane];
    const u32 klo = (u32)myk, khi = (u32)(myk >> 32);
    // keep-alive (rule #17): keeps sExt scatter, rank loop, sR writes, ladder
    asm volatile("" :: "v"(klo), "v"(khi));
}

// ---------------------------------------------------------------------------
// Real kernel: ROUND 28 VERBATIM (42.2us, absmax 0)
// ---------------------------------------------------------------------------
__global__ void __launch_bounds__(TPB, 8) knn_kernel(
    const float* __restrict__ CB, const float* __restrict__ maskA,
    const float* __restrict__ Y, const int* __restrict__ Yt,
    const int* __restrict__ Ym, float* __restrict__ out)
{
    __shared__ __align__(16) float sX[CAP];
    __shared__ __align__(16) float sY[CAP];
    __shared__ __align__(16) float sZ[CAP];
    __shared__ u16 sP16[CAP];
    __shared__ u16 sMidx[64];
    __shared__ int sWinc[16];
    __shared__ int sWbase[16];
    __shared__ int sVtot;
    __shared__ u64 sExt[WPB][64];
    __shared__ u64 sR[WPB][KK];

    const int tid  = threadIdx.x;
    const int lane = tid & 63;
    const int wv   = tid >> 6;
    const int blk  = blockIdx.x;
    const int b    = blk >> 7;
    const int qg   = blk & 127;

    const float* Yb  = Y  + (size_t)b * MM * 3;
    const int*   Ymb = Ym + (size_t)b * MM;
    const int*   Ytb = Yt + (size_t)b * MM;

    const int p0 = tid << 2;
    const float4 f0 = *(const float4*)(Yb + 3 * p0);
    const float4 f1 = *(const float4*)(Yb + 3 * p0 + 4);
    const float4 f2 = *(const float4*)(Yb + 3 * p0 + 8);
    const int4   m4 = *(const int4*)(Ymb + p0);
    const int v0 = (m4.x != 0), v1 = (m4.y != 0), v2 = (m4.z != 0), v3 = (m4.w != 0);
    const int cnt0 = v0 + v1 + v2 + v3;

    int inc = cnt0;
#pragma unroll
    for (int off = 1; off < 64; off <<= 1) {
        const int t = __shfl_up(inc, off, 64);
        if (lane >= off) inc += t;
    }
    if (lane == 63) sWinc[wv] = inc;
    __syncthreads();
    if (tid < 16) {
        const int x = sWinc[tid];
        int ix = x;
#pragma unroll
        for (int off = 1; off < 16; off <<= 1) {
            const int t = __shfl_up(ix, off, 16);
            if (tid >= off) ix += t;
        }
        sWbase[tid] = ix - x;
        if (tid == 15) sVtot = ix;
    }
    __syncthreads();

    {
        int bs = sWbase[wv] + inc - cnt0;
        int mb = p0 - bs;
        if (v0) { sX[bs]=f0.x; sY[bs]=f0.y; sZ[bs]=f0.z; sP16[bs]=(u16)(p0+0); bs++; }
        else    { if (mb < 64) sMidx[mb] = (u16)(p0 + 0); mb++; }
        if (v1) { sX[bs]=f0.w; sY[bs]=f1.x; sZ[bs]=f1.y; sP16[bs]=(u16)(p0+1); bs++; }
        else    { if (mb < 64) sMidx[mb] = (u16)(p0 + 1); mb++; }
        if (v2) { sX[bs]=f1.z; sY[bs]=f1.w; sZ[bs]=f2.x; sP16[bs]=(u16)(p0+2); bs++; }
        else    { if (mb < 64) sMidx[mb] = (u16)(p0 + 2); mb++; }
        if (v3) { sX[bs]=f2.y; sY[bs]=f2.z; sZ[bs]=f2.w; sP16[bs]=(u16)(p0+3); bs++; }
        else    { if (mb < 64) sMidx[mb] = (u16)(p0 + 3); mb++; }
    }
    const int V  = sVtot;
    const int NJ = (V + 127) >> 7;
    for (int c = V + tid; c < (NJ << 7); c += TPB) {
        sX[c] = __builtin_inff(); sY[c] = 0.0f; sZ[c] = 0.0f; sP16[c] = 4095;
    }
    __syncthreads();

    const int l = qg * WPB + wv;
    const int q = b * LL + l;

    float* out_y = out;
    float* out_t = out + (size_t)BB * LL * KK * 3;
    float* out_m = out_t + (size_t)BB * LL * KK;
    float* out_d = out_m + (size_t)BB * LL * KK;

    if (maskA[q] == 0.0f) {
        if (lane < KK) {
            const int p = lane;
            const size_t o = (size_t)q * KK + lane;
            out_y[3 * o + 0] = Yb[3 * p + 0];
            out_y[3 * o + 1] = Yb[3 * p + 1];
            out_y[3 * o + 2] = Yb[3 * p + 2];
            out_t[o] = (float)Ytb[p];
            out_m[o] = (float)Ymb[p];
            if (lane == 0) out_d[q] = sqrtf(1000.0f);
        }
        return;
    }

    const float cx = CB[3 * q + 0];
    const float cy = CB[3 * q + 1];
    const float cz = CB[3 * q + 2];

    float v1f = 3.0e38f, v2f = 3.0e38f, v3f = 3.0e38f, v4f = 3.0e38f;
    u32 J = 0u;
    const u32 SEL1 = 0x06050400u;
    const u32 SEL2 = 0x06050004u;
    const u32 SEL3 = 0x06000504u;
    const u32 SEL4 = 0x00060504u;
    auto ins = [&](float v, u32 id) {
        const bool c1 = v < v1f, c2 = v < v2f, c3 = v < v3f, c4 = v < v4f;
        const u32 sel = c1 ? SEL1 : (c2 ? SEL2 : (c3 ? SEL3 : SEL4));
        const u32 Jp  = __builtin_amdgcn_perm(J, id, sel);
        const float n2 = __builtin_amdgcn_fmed3f(v, v1f, v2f);
        const float n3 = __builtin_amdgcn_fmed3f(v, v2f, v3f);
        const float n4 = __builtin_amdgcn_fmed3f(v, v3f, v4f);
        v1f = fminf(v, v1f);
        v2f = n2; v3f = n3; v4f = n4;
        J = c4 ? Jp : J;
    };

    const f32x2 cxx = {cx, cx}, cyy = {cy, cy}, czz = {cz, cz};
#pragma unroll 4
    for (int j = 0; j < NJ; ++j) {
        const int base = (j << 7) + (lane << 1);
        const f32x2 xp = *(const f32x2*)&sX[base];
        const f32x2 yp = *(const f32x2*)&sY[base];
        const f32x2 zp = *(const f32x2*)&sZ[base];
        const f32x2 dx = cxx - xp;
        const f32x2 dy = cyy - yp;
        const f32x2 dz = czz - zp;
        const f32x2 dsq = (dx * dx + dy * dy) + dz * dz;
        ins(dsq.x, (u32)(j << 1));
        ins(dsq.y, (u32)((j << 1) | 1));
    }

    auto slotof = [&](u32 id) -> u32 {
        return ((id >> 1) << 7) | (u32)(lane << 1) | (id & 1u);
    };

    const u32 s1 = slotof( J        & 0xFFu);
    const u32 s2 = slotof((J >>  8) & 0xFFu);
    const u32 s3 = slotof((J >> 16) & 0xFFu);
    const u32 s4 = slotof((J >> 24) & 0xFFu);
    u32 h1 = __float_as_uint(v1f) + 1u;
    u32 h2 = __float_as_uint(v2f) + 1u;
    u32 h3 = __float_as_uint(v3f) + 1u;
    u32 h4 = __float_as_uint(v4f) + 1u;
    u64 lref = ((u64)h4 << 32) | s4;

    bool ladder = false;
    int  rstart = 0;
    {
        const u32 T = wave_min_u32(h4);
        const bool c1 = (h1 <= T), c2 = (h2 <= T), c3 = (h3 <= T), c4 = (h4 <= T);
        const u64 b1 = __ballot(c1), b2 = __ballot(c2);
        const u64 b3 = __ballot(c3), b4 = __ballot(c4);
        const int n1 = __popcll(b1), n2 = __popcll(b2), n3 = __popcll(b3);
        const int total = n1 + n2 + n3 + __popcll(b4);
        if (total > 64) {
            ladder = true;
        } else {
            const u64 below = (1ull << lane) - 1ull;
            u64* sE = sExt[wv];
            sE[lane] = SENT;
            if (lane == 24) sR[wv][24] = SENT;
            int pos = __popcll(b1 & below);
            if (c1) sE[pos] = ((u64)h1 << 32) | s1;
            pos = n1 + __popcll(b2 & below);
            if (c2) sE[pos] = ((u64)h2 << 32) | s2;
            pos = n1 + n2 + __popcll(b3 & below);
            if (c3) sE[pos] = ((u64)h3 << 32) | s3;
            pos = n1 + n2 + n3 + __popcll(b4 & below);
            if (c4) sE[pos] = ((u64)h4 << 32) | s4;
            const u64 mk = sE[lane];
            int rank = 0;
            const int tot = (total + 7) & ~7;
#pragma unroll 8
            for (int i = 0; i < tot; ++i)
                rank += (sE[i] < mk) ? 1 : 0;
            if (rank < KK && mk != SENT) sR[wv][rank] = mk;
            const u64 K25 = sR[wv][24];
            if (__any(lref < K25)) {
                const int scnt = (h1 < T) + (h2 < T) + (h3 < T) + (h4 < T);
                rstart = __popcll(__ballot(h1 < T)) + __popcll(__ballot(h2 < T))
                       + __popcll(__ballot(h3 < T)) + __popcll(__ballot(h4 < T));
#pragma unroll
                for (int k = 0; k < 4; ++k)
                    if (k < scnt) { h1 = h2; h2 = h3; h3 = h4; h4 = SENTH; J >>= 8; }
                ladder = true;
            }
        }
    }

    if (ladder) {
#pragma unroll 1
        for (int it = rstart; it < KK; ++it) {
            if (__any(h1 == SENTH)) {
                const bool need = (h1 == SENTH);
                u64 found = SENT;
                const int NI = NJ << 1;
#pragma unroll 4
                for (int id = 0; id < NI; ++id) {
                    const u32 s = slotof((u32)id);
                    const float dx = cx - sX[s];
                    const float dy = cy - sY[s];
                    const float dz = cz - sZ[s];
                    const float v = (dx * dx + dy * dy) + dz * dz;
                    const u64 key = ((u64)(__float_as_uint(v) + 1u) << 32) | s;
                    if (key > lref && key < found) found = key;
                }
                if (need) {
                    const u32 s = (u32)found & 0xFFFFu;
                    h1 = (u32)(found >> 32);
                    J = (J & ~0xFFu) | (((s >> 7) << 1) | (s & 1u));
                    lref = found;
                }
            }
            const u32 bv = wave_min_u32(h1);
            const u64 ball = __ballot(h1 == bv);
            bool win = (h1 == bv);
            if (__popcll(ball) != 1) {
                const u32 vl = slotof(J & 0xFFu);
                u32 cp = win ? vl : 0xFFFFFFFFu;
#pragma unroll
                for (int off = 32; off; off >>= 1) {
                    const u32 o = __shfl_xor(cp, off, 64);
                    cp = (o < cp) ? o : cp;
                }
                win = win && (vl == cp);
            }
            if (win) {
                sR[wv][it] = ((u64)h1 << 32) | slotof(J & 0xFFu);
                h1 = h2; h2 = h3; h3 = h4; h4 = SENTH;
                J >>= 8;
            }
        }
    }

    u64 myk = 0;
    if (lane < KK) myk = sR[wv][lane];
    const u32 mvh   = (u32)(myk >> 32);
    const u32 mslot = (u32)myk & 0xFFFFu;
    const bool less = (lane < KK) && (mvh < 0x447A0001u);
    const int nless = __popcll(__ballot(less));
    if (lane < KK) {
        int p; float val, mflag;
        if (lane < nless) {
            p = (int)sP16[mslot];
            val = __uint_as_float(mvh - 1u);
            mflag = 1.0f;
        } else {
            p = (int)sMidx[lane - nless];
            val = 1000.0f;
            mflag = 0.0f;
        }
        const size_t o = (size_t)q * KK + lane;
        out_y[3 * o + 0] = Yb[3 * p + 0];
        out_y[3 * o + 1] = Yb[3 * p + 1];
        out_y[3 * o + 2] = Yb[3 * p + 2];
        out_t[o] = (float)Ytb[p];
        out_m[o] = mflag;
        if (lane == 0) out_d[q] = sqrtf(val);
    }
}

extern "C" void kernel_launch(void* const* d_in, const int* in_sizes, int n_in,
                              void* d_out, int out_size, void* d_ws, size_t ws_size,
                              hipStream_t stream) {
    const float* CB   = (const float*)d_in[0];
    const float* mask = (const float*)d_in[1];
    const float* Y    = (const float*)d_in[2];
    const int*   Yt   = (const int*)d_in[3];
    const int*   Ym   = (const int*)d_in[4];
    float* out = (float*)d_out;

    // measurement stub: staging+main+selection+ladder, 4x rounds, no writes
    hipLaunchKernelGGL(knn_selstub, dim3(4096), dim3(TPB), 0, stream,
                       CB, mask, Y, Yt, Ym);
    // real kernel (r28 verbatim)
    hipLaunchKernelGGL(knn_kernel, dim3(BB * LL / WPB), dim3(TPB), 0, stream,
                       CB, mask, Y, Yt, Ym, out);
}

// Round 19
// 100.047 us; speedup vs baseline: 2.2303x; 2.2303x over previous
//
#include <hip/hip_runtime.h>

// Forbid FMA contraction EVERYWHERE: distances must be bit-identical to
// numpy's unfused ((dx*dx + dy*dy) + dz*dz) in main loop AND fallback.
#pragma clang fp contract(off)

typedef unsigned long long u64;
typedef unsigned int u32;
typedef unsigned short u16;
typedef float f32x2 __attribute__((ext_vector_type(2)));

#define BB 8
#define LL 2048
#define MM 4096
#define KK 25
#define WPB 16           // waves (queries) per block
#define TPB 1024
#define CAP 3072         // compacted-valid capacity (V ~ 2048 +- 32; P(V>CAP)~0)
#define SENT  0xFFFFFFFFFFFFFFFFull
#define SENTH 0xFFFFFFFFu   // exhausted marker for value words (> inf-bits+1)

// Wave64 min-reduce -> wave-uniform scalar (proven round-9 DPP ladder).
static __device__ __forceinline__ u32 wave_min_u32(u32 x) {
    u32 t;
    t = (u32)__builtin_amdgcn_update_dpp(0, (int)x, 0xB1, 0xF, 0xF, true);   // xor1
    x = t < x ? t : x;
    t = (u32)__builtin_amdgcn_update_dpp(0, (int)x, 0x4E, 0xF, 0xF, true);   // xor2
    x = t < x ? t : x;
    t = (u32)__builtin_amdgcn_update_dpp(0, (int)x, 0x141, 0xF, 0xF, true);  // half-row mirror
    x = t < x ? t : x;
    t = (u32)__builtin_amdgcn_update_dpp(0, (int)x, 0x140, 0xF, 0xF, true);  // row mirror
    x = t < x ? t : x;
    t = (u32)__builtin_amdgcn_update_dpp((int)x, (int)x, 0x142, 0xF, 0xF, false); // row_bcast15
    x = t < x ? t : x;
    t = (u32)__builtin_amdgcn_update_dpp((int)x, (int)x, 0x143, 0xF, 0xF, false); // row_bcast31
    x = t < x ? t : x;
    return (u32)__builtin_amdgcn_readlane((int)x, 63);
}

// ROUND 30 = r28 (42.2us, absmax 0) + epilogue served from LDS.
// r29 measurement closed the ledger ADDITIVELY: staging+main 24.6 +
// selection/fire 10.3 + merge/epilogue 7.3 = 42.2. The 7.3us epilogue is
// the scattered winner gather: 25 random-p Yb[3p]/Ytb[p] reads per query
// ~ 50 cache lines x 16K queries ~ 50MB L2 gather. Fix (zero LDS growth):
// the valid-winner path never needs p itself — coords live in sX/sY/sZ
// [slot], Ym[p]==1 by construction, and sP16[slot] is REPURPOSED to hold
// Yt (0..63 fits u16; staging loads an extra coalesced int4 of Yt).
// Global gathers remain only for rare outlier masked-run entries and the
// 10% masked-query fast path. out_d: nless==0 => lane0 masked branch =>
// sqrt(1000) (reference-exact). All else verbatim r28.
__global__ void __launch_bounds__(TPB, 8) knn_kernel(
    const float* __restrict__ CB, const float* __restrict__ maskA,
    const float* __restrict__ Y, const int* __restrict__ Yt,
    const int* __restrict__ Ym, float* __restrict__ out)
{
    __shared__ __align__(16) float sX[CAP];   // 12 KiB each
    __shared__ __align__(16) float sY[CAP];
    __shared__ __align__(16) float sZ[CAP];
    __shared__ u16 sT16[CAP];                 // slot -> Yt value (6 KiB)
    __shared__ u16 sMidx[64];                 // first 64 masked indices (p order)
    __shared__ int sWinc[16];
    __shared__ int sWbase[16];
    __shared__ int sVtot;
    __shared__ u64 sExt[WPB][64];             // survivor scatter (8 KiB)
    __shared__ u64 sR[WPB][KK];               // rank->key (3.2 KiB)

    const int tid  = threadIdx.x;
    const int lane = tid & 63;
    const int wv   = tid >> 6;
    const int blk  = blockIdx.x;
    const int b    = blk >> 7;        // 128 blocks per batch (LL/WPB)
    const int qg   = blk & 127;

    const float* Yb  = Y  + (size_t)b * MM * 3;
    const int*   Ymb = Ym + (size_t)b * MM;
    const int*   Ytb = Yt + (size_t)b * MM;

    // ---- staging: stable compaction of valid candidates (r16, proven) ----
    const int p0 = tid << 2;
    const float4 f0 = *(const float4*)(Yb + 3 * p0);
    const float4 f1 = *(const float4*)(Yb + 3 * p0 + 4);
    const float4 f2 = *(const float4*)(Yb + 3 * p0 + 8);
    const int4   m4 = *(const int4*)(Ymb + p0);
    const int4   t4 = *(const int4*)(Ytb + p0);
    const int v0 = (m4.x != 0), v1 = (m4.y != 0), v2 = (m4.z != 0), v3 = (m4.w != 0);
    const int cnt0 = v0 + v1 + v2 + v3;

    int inc = cnt0;
#pragma unroll
    for (int off = 1; off < 64; off <<= 1) {
        const int t = __shfl_up(inc, off, 64);
        if (lane >= off) inc += t;
    }
    if (lane == 63) sWinc[wv] = inc;
    __syncthreads();
    if (tid < 16) {
        const int x = sWinc[tid];
        int ix = x;
#pragma unroll
        for (int off = 1; off < 16; off <<= 1) {
            const int t = __shfl_up(ix, off, 16);
            if (tid >= off) ix += t;
        }
        sWbase[tid] = ix - x;
        if (tid == 15) sVtot = ix;
    }
    __syncthreads();

    {
        int bs = sWbase[wv] + inc - cnt0;
        int mb = p0 - bs;
        if (v0) { sX[bs]=f0.x; sY[bs]=f0.y; sZ[bs]=f0.z; sT16[bs]=(u16)t4.x; bs++; }
        else    { if (mb < 64) sMidx[mb] = (u16)(p0 + 0); mb++; }
        if (v1) { sX[bs]=f0.w; sY[bs]=f1.x; sZ[bs]=f1.y; sT16[bs]=(u16)t4.y; bs++; }
        else    { if (mb < 64) sMidx[mb] = (u16)(p0 + 1); mb++; }
        if (v2) { sX[bs]=f1.z; sY[bs]=f1.w; sZ[bs]=f2.x; sT16[bs]=(u16)t4.z; bs++; }
        else    { if (mb < 64) sMidx[mb] = (u16)(p0 + 2); mb++; }
        if (v3) { sX[bs]=f2.y; sY[bs]=f2.z; sZ[bs]=f2.w; sT16[bs]=(u16)t4.w; bs++; }
        else    { if (mb < 64) sMidx[mb] = (u16)(p0 + 3); mb++; }
    }
    const int V  = sVtot;
    const int NJ = (V + 127) >> 7;            // 128-slot blocks (~16)
    for (int c = V + tid; c < (NJ << 7); c += TPB) {
        sX[c] = __builtin_inff(); sY[c] = 0.0f; sZ[c] = 0.0f; sT16[c] = 0;
    }
    __syncthreads();

    const int l = qg * WPB + wv;
    const int q = b * LL + l;

    float* out_y = out;
    float* out_t = out + (size_t)BB * LL * KK * 3;
    float* out_m = out_t + (size_t)BB * LL * KK;
    float* out_d = out_m + (size_t)BB * LL * KK;

    // ---- fast path: masked query (verified r2..r28) ----
    if (maskA[q] == 0.0f) {
        if (lane < KK) {
            const int p = lane;
            const size_t o = (size_t)q * KK + lane;
            out_y[3 * o + 0] = Yb[3 * p + 0];
            out_y[3 * o + 1] = Yb[3 * p + 1];
            out_y[3 * o + 2] = Yb[3 * p + 2];
            out_t[o] = (float)Ytb[p];
            out_m[o] = (float)Ymb[p];
            if (lane == 0) out_d[q] = sqrtf(1000.0f);
        }
        return;
    }

    const float cx = CB[3 * q + 0];
    const float cy = CB[3 * q + 1];
    const float cz = CB[3 * q + 2];

    // ---- fused packed distance + per-lane stable top-4 (asc by (v,slot)) --
    float v1f = 3.0e38f, v2f = 3.0e38f, v3f = 3.0e38f, v4f = 3.0e38f;
    u32 J = 0u;                     // byte-packed ids id=(j<<1)|half
    const u32 SEL1 = 0x06050400u;
    const u32 SEL2 = 0x06050004u;
    const u32 SEL3 = 0x06000504u;
    const u32 SEL4 = 0x00060504u;
    auto ins = [&](float v, u32 id) {
        const bool c1 = v < v1f, c2 = v < v2f, c3 = v < v3f, c4 = v < v4f;
        const u32 sel = c1 ? SEL1 : (c2 ? SEL2 : (c3 ? SEL3 : SEL4));
        const u32 Jp  = __builtin_amdgcn_perm(J, id, sel);
        const float n2 = __builtin_amdgcn_fmed3f(v, v1f, v2f);
        const float n3 = __builtin_amdgcn_fmed3f(v, v2f, v3f);
        const float n4 = __builtin_amdgcn_fmed3f(v, v3f, v4f);
        v1f = fminf(v, v1f);
        v2f = n2; v3f = n3; v4f = n4;
        J = c4 ? Jp : J;
    };

    const f32x2 cxx = {cx, cx}, cyy = {cy, cy}, czz = {cz, cz};
#pragma unroll 4
    for (int j = 0; j < NJ; ++j) {
        const int base = (j << 7) + (lane << 1);
        const f32x2 xp = *(const f32x2*)&sX[base];
        const f32x2 yp = *(const f32x2*)&sY[base];
        const f32x2 zp = *(const f32x2*)&sZ[base];
        const f32x2 dx = cxx - xp;
        const f32x2 dy = cyy - yp;
        const f32x2 dz = czz - zp;
        const f32x2 dsq = (dx * dx + dy * dy) + dz * dz;
        ins(dsq.x, (u32)(j << 1));          // slot 2*lane   (lower p)
        ins(dsq.y, (u32)((j << 1) | 1));    // slot 2*lane+1
    }

    auto slotof = [&](u32 id) -> u32 {
        return ((id >> 1) << 7) | (u32)(lane << 1) | (id & 1u);
    };

    const u32 s1 = slotof( J        & 0xFFu);
    const u32 s2 = slotof((J >>  8) & 0xFFu);
    const u32 s3 = slotof((J >> 16) & 0xFFu);
    const u32 s4 = slotof((J >> 24) & 0xFFu);
    u32 h1 = __float_as_uint(v1f) + 1u;
    u32 h2 = __float_as_uint(v2f) + 1u;
    u32 h3 = __float_as_uint(v3f) + 1u;
    u32 h4 = __float_as_uint(v4f) + 1u;
    u64 lref = ((u64)h4 << 32) | s4;     // refill anchor (updated on refill)

    // ---- flat parallel selection; fire -> resumed ladder (r26, proven) ----
    bool ladder = false;
    int  rstart = 0;
    {
        const u32 T = wave_min_u32(h4);   // wave-uniform; depth-6 DPP ladder
        const bool c1 = (h1 <= T), c2 = (h2 <= T), c3 = (h3 <= T), c4 = (h4 <= T);
        const u64 b1 = __ballot(c1), b2 = __ballot(c2);
        const u64 b3 = __ballot(c3), b4 = __ballot(c4);
        const int n1 = __popcll(b1), n2 = __popcll(b2), n3 = __popcll(b3);
        const int total = n1 + n2 + n3 + __popcll(b4);
        if (total > 64) {
            ladder = true;                // P~0: full ladder, chain unshifted
        } else {
            const u64 below = (1ull << lane) - 1ull;
            u64* sE = sExt[wv];
            sE[lane] = SENT;              // pad [total,64)
            if (lane == 24) sR[wv][24] = SENT;   // incomplete-detector
            int pos = __popcll(b1 & below);
            if (c1) sE[pos] = ((u64)h1 << 32) | s1;
            pos = n1 + __popcll(b2 & below);
            if (c2) sE[pos] = ((u64)h2 << 32) | s2;
            pos = n1 + n2 + __popcll(b3 & below);
            if (c3) sE[pos] = ((u64)h3 << 32) | s3;
            pos = n1 + n2 + n3 + __popcll(b4 & below);
            if (c4) sE[pos] = ((u64)h4 << 32) | s4;
            const u64 mk = sE[lane];
            // rank = #(survivors < mine): broadcast reads, zero serial depth
            int rank = 0;
            const int tot = (total + 7) & ~7;
#pragma unroll 8
            for (int i = 0; i < tot; ++i)
                rank += (sE[i] < mk) ? 1 : 0;
            if (rank < KK && mk != SENT) sR[wv][rank] = mk;
            const u64 K25 = sR[wv][24];   // broadcast; SENT if survivors<25
            if (__any(lref < K25)) {
                // ranks with value < T strictly are unconditionally correct
                // (hidden keys all have value >= T). Resume after them.
                const int scnt = (h1 < T) + (h2 < T) + (h3 < T) + (h4 < T);
                rstart = __popcll(__ballot(h1 < T)) + __popcll(__ballot(h2 < T))
                       + __popcll(__ballot(h3 < T)) + __popcll(__ballot(h4 < T));
                // shift chain past this lane's consumed (value<T) survivors
#pragma unroll
                for (int k = 0; k < 4; ++k)
                    if (k < scnt) { h1 = h2; h2 = h3; h3 = h4; h4 = SENTH; J >>= 8; }
                ladder = true;            // fire => rstart <= 24 (proven)
            }
        }
    }

    // ---- resumed serial extraction (r19/r26 body, proven), winners -> sR --
    if (ladder) {
#pragma unroll 1
        for (int it = rstart; it < KK; ++it) {
            if (__any(h1 == SENTH)) {
                const bool need = (h1 == SENTH);
                u64 found = SENT;
                const int NI = NJ << 1;
#pragma unroll 4
                for (int id = 0; id < NI; ++id) {
                    const u32 s = slotof((u32)id);
                    const float dx = cx - sX[s];
                    const float dy = cy - sY[s];
                    const float dz = cz - sZ[s];
                    const float v = (dx * dx + dy * dy) + dz * dz;
                    const u64 key = ((u64)(__float_as_uint(v) + 1u) << 32) | s;
                    if (key > lref && key < found) found = key;
                }
                if (need) {
                    const u32 s = (u32)found & 0xFFFFu;
                    h1 = (u32)(found >> 32);
                    J = (J & ~0xFFu) | (((s >> 7) << 1) | (s & 1u));
                    lref = found;
                }
            }
            const u32 bv = wave_min_u32(h1);
            const u64 ball = __ballot(h1 == bv);
            bool win = (h1 == bv);
            if (__popcll(ball) != 1) {        // exact value tie: min slot wins
                const u32 vl = slotof(J & 0xFFu);
                u32 cp = win ? vl : 0xFFFFFFFFu;
#pragma unroll
                for (int off = 32; off; off >>= 1) {
                    const u32 o = __shfl_xor(cp, off, 64);
                    cp = (o < cp) ? o : cp;
                }
                win = win && (vl == cp);
            }
            if (win) {                        // unique keys -> exactly one lane
                sR[wv][it] = ((u64)h1 << 32) | slotof(J & 0xFFu);
                h1 = h2; h2 = h3; h3 = h4; h4 = SENTH;
                J >>= 8;
            }
        }
    }

    // ---- merge valid winners with the constant masked run, then output ----
    // Valid winners served from LDS: coords sX/sY/sZ[slot], Yt from sT16,
    // Ym==1 by construction. Global gathers only for masked-run entries.
    u64 myk = 0;
    if (lane < KK) myk = sR[wv][lane];
    const u32 mvh   = (u32)(myk >> 32);
    const u32 mslot = (u32)myk & 0xFFFFu;
    const bool less = (lane < KK) && (mvh < 0x447A0001u);  // v < 1000.0f
    const int nless = __popcll(__ballot(less));
    if (lane < KK) {
        const size_t o = (size_t)q * KK + lane;
        if (lane < nless) {
            out_y[3 * o + 0] = sX[mslot];
            out_y[3 * o + 1] = sY[mslot];
            out_y[3 * o + 2] = sZ[mslot];
            out_t[o] = (float)sT16[mslot];
            out_m[o] = 1.0f;
            if (lane == 0) out_d[q] = sqrtf(__uint_as_float(mvh - 1u));
        } else {
            const int p = (int)sMidx[lane - nless];
            out_y[3 * o + 0] = Yb[3 * p + 0];
            out_y[3 * o + 1] = Yb[3 * p + 1];
            out_y[3 * o + 2] = Yb[3 * p + 2];
            out_t[o] = (float)Ytb[p];
            out_m[o] = 0.0f;
            if (lane == 0) out_d[q] = sqrtf(1000.0f);   // nless==0 outlier
        }
    }
}

extern "C" void kernel_launch(void* const* d_in, const int* in_sizes, int n_in,
                              void* d_out, int out_size, void* d_ws, size_t ws_size,
                              hipStream_t stream) {
    const float* CB   = (const float*)d_in[0];
    const float* mask = (const float*)d_in[1];
    const float* Y    = (const float*)d_in[2];
    const int*   Yt   = (const int*)d_in[3];
    const int*   Ym   = (const int*)d_in[4];
    float* out = (float*)d_out;

    dim3 grid(BB * LL / WPB);
    dim3 block(TPB);
    hipLaunchKernelGGL(knn_kernel, grid, block, 0, stream, CB, mask, Y, Yt, Ym, out);
}